// Round 10
// baseline (934.207 us; speedup 1.0000x reference)
//
#include <hip/hip_runtime.h>
#include <math.h>

#define NC1 150
#define HW 196          // 14*14
#define CST 153         // As row stride: odd -> conflict-free scalar ds access
#define NTOTF (HW*CST)  // 29988 (divisible by 4)
#define NB 1024
#define DD 32
#define NHD 4
#define HDIM 8
#define KG 2352         // ceil(0.08 * 150*14*14)
#define KCH 10

#define XT_OFF 0        // X^T [21][196] floats
#define WT_OFF 4116     // W^T [21][152] floats
#define UNIONF 7308     // union floats (CE[150][33]=4950 overlays later)

// ---------------- K0: 2D sinusoidal positional embedding [196,32] ----------------
__global__ void pos2d_kernel(float* __restrict__ pos) {
  int i = blockIdx.x * 256 + threadIdx.x;
  if (i >= HW * DD) return;
  int s = i >> 5, d = i & 31;
  int h = s / 14, w = s % 14;
  int p = (d < 16) ? h : w;
  int dd = (d < 16) ? d : d - 16;
  int j = dd >> 1;
  float dv = expf(-(logf(10000.0f) / 16.0f) * (float)(2 * j));
  float ang = (float)p * dv;
  pos[i] = (dd & 1) ? cosf(ang) : sinf(ang);
}

// ---------------- K1 (fused): im2col-GEMM conv -> LDS radix kth -> top10+embed ----
// R9-proven: DO NOT TOUCH (308us, no spill, correct).
__global__ __launch_bounds__(1024, 4) void fused_kernel(const float* __restrict__ x,
                                                        const float* __restrict__ cw,
                                                        const float* __restrict__ CE,
                                                        const float* __restrict__ pos,
                                                        float* __restrict__ seqo) {
  __shared__ alignas(16) float As[NTOTF];     // 119952 B
  __shared__ alignas(16) float ubuf[UNIONF];  // 29232 B: XT|WT, later CE[150][33]
  __shared__ alignas(16) float xs[784];       // 3136 B
  __shared__ unsigned hist[2048];             // 8192 B
  __shared__ unsigned wsum[4];
  __shared__ unsigned s_prefix, s_krem, s_max;   // total ~160.5 KB

  int b = blockIdx.x, tid = threadIdx.x;
  int lane = tid & 63, wid = tid >> 6;

  if (tid < 196) ((float4*)xs)[tid] = ((const float4*)(x + (size_t)b * 784))[tid];
  if (tid == 0) { s_prefix = 0u; s_krem = KG; s_max = 0u; }
  __syncthreads();

  int cg = tid / 49;              // ch-group 0..18 (8 ch each, 152 incl 2 pad)
  int g  = tid - cg * 49;         // loc-group 0..48 (4 locs each, 196 exact)
  bool act = (tid < 931);         // 19*49
  float acc[4][8];
#pragma unroll
  for (int i = 0; i < 4; ++i)
#pragma unroll
    for (int j = 0; j < 8; ++j) acc[i][j] = 0.f;

  float* XT = ubuf + XT_OFF;      // [21][196]
  float* WT = ubuf + WT_OFF;      // [21][152]

  for (int kb = 0; kb < 84; kb += 21) {
    __syncthreads();              // previous-phase XT/WT readers done
    for (int i = tid; i < 21 * 196; i += 1024) {
      int kk = i / 196, s = i - kk * 196;
      int k = kb + kk;
      float v = 0.f;
      if (k < 81) {
        int ki = k / 9, kj = k - ki * 9;
        int h = s / 14, w = s - h * 14;
        int r = 2 * h - 4 + ki, c = 2 * w - 4 + kj;
        if (r >= 0 && r < 28 && c >= 0 && c < 28) v = xs[r * 28 + c];
      }
      XT[i] = v;
    }
    for (int i = tid; i < 21 * 152; i += 1024) {
      int kk = i / 152, c = i - kk * 152;
      int k = kb + kk;
      WT[i] = (k < 81 && c < NC1) ? cw[c * 81 + k] : 0.f;
    }
    __syncthreads();
    if (act) {
      const float* xtp = XT + 4 * g;
      const float* wtp = WT + 8 * cg;
#pragma unroll 7
      for (int kk = 0; kk < 21; ++kk) {
        float4 xv = *(const float4*)(xtp + kk * 196);
        float4 w0 = *(const float4*)(wtp + kk * 152);
        float4 w1 = *(const float4*)(wtp + kk * 152 + 4);
        float xa[4] = {xv.x, xv.y, xv.z, xv.w};
        float wa[8] = {w0.x, w0.y, w0.z, w0.w, w1.x, w1.y, w1.z, w1.w};
#pragma unroll
        for (int i = 0; i < 4; ++i)
#pragma unroll
          for (int j = 0; j < 8; ++j) acc[i][j] += xa[i] * wa[j];
      }
    }
  }
  __syncthreads();
  if (act) {
#pragma unroll
    for (int i = 0; i < 4; ++i) {
      float* dst = As + (4 * g + i) * CST + 8 * cg;
#pragma unroll
      for (int j = 0; j < 8; ++j) dst[j] = fmaxf(acc[i][j], 0.f);
    }
  }
  if (tid < 196) As[tid * CST + 152] = 0.f;
  __syncthreads();

  float* CEs = ubuf;
  for (int i = tid; i < NC1 * 32; i += 1024) {
    int c = i >> 5, e = i & 31;
    CEs[c * 33 + e] = CE[i];
  }

  unsigned mymax = 0u;
  __syncthreads();
  const float4* Ab = (const float4*)As;
  for (int pass = 0; pass < 3; ++pass) {
    hist[tid] = 0u; hist[tid + 1024] = 0u;
    __syncthreads();
    int shift = (pass == 0) ? 21 : (pass == 1 ? 10 : 0);
    int bits = (pass == 2) ? 10 : 11;
    unsigned mask = (1u << bits) - 1u;
    unsigned pfx = s_prefix;
    unsigned krem = s_krem;
    int hishift = shift + bits;
    for (int i = tid; i < NTOTF / 4; i += 1024) {
      float4 f = Ab[i];
      unsigned u0 = __float_as_uint(f.x), u1 = __float_as_uint(f.y);
      unsigned u2 = __float_as_uint(f.z), u3 = __float_as_uint(f.w);
      if (pass == 0) {
        mymax = max(mymax, max(max(u0, u1), max(u2, u3)));
        if (u0) atomicAdd(&hist[u0 >> 21], 1u);
        if (u1) atomicAdd(&hist[u1 >> 21], 1u);
        if (u2) atomicAdd(&hist[u2 >> 21], 1u);
        if (u3) atomicAdd(&hist[u3 >> 21], 1u);
      } else {
        if (u0 && (u0 >> hishift) == pfx) atomicAdd(&hist[(u0 >> shift) & mask], 1u);
        if (u1 && (u1 >> hishift) == pfx) atomicAdd(&hist[(u1 >> shift) & mask], 1u);
        if (u2 && (u2 >> hishift) == pfx) atomicAdd(&hist[(u2 >> shift) & mask], 1u);
        if (u3 && (u3 >> hishift) == pfx) atomicAdd(&hist[(u3 >> shift) & mask], 1u);
      }
    }
    if (pass == 0) atomicMax(&s_max, mymax);
    __syncthreads();
    int segsz = (1 << bits) >> 8;
    unsigned segv = 0u, sufv = 0u;
    if (tid < 256) {
      for (int j = 0; j < segsz; ++j) segv += hist[tid * segsz + j];
      sufv = segv;
#pragma unroll
      for (int st = 1; st < 64; st <<= 1) {
        unsigned o = (unsigned)__shfl_down((int)sufv, st);
        if (lane + st < 64) sufv += o;
      }
      if (lane == 0) wsum[wid] = sufv;
    }
    __syncthreads();
    if (tid < 256) {
      unsigned tail = 0u;
      for (int ww = wid + 1; ww < 4; ++ww) tail += wsum[ww];
      sufv += tail;
      unsigned above = sufv - segv;
      if (above < krem && sufv >= krem) {
        unsigned cum = above;
        int dsel = tid * segsz;
        for (int d2 = segsz - 1; d2 >= 0; --d2) {
          int dd = tid * segsz + d2;
          if (cum + hist[dd] >= krem) { dsel = dd; break; }
          cum += hist[dd];
        }
        s_prefix = (pfx << bits) | (unsigned)dsel;
        s_krem = krem - cum;
      }
    }
    __syncthreads();
  }

  float T = __uint_as_float(s_prefix);
  float gm = __uint_as_float(s_max);
  float gi = (gm == 0.0f) ? 0.0f : 1.0f / gm;
  if (tid < 196) {
    const float* row = As + tid * CST;
    float tv[KCH]; int tc[KCH];
#pragma unroll
    for (int k = 0; k < KCH; ++k) { tv[k] = -1.0f; tc[k] = 0; }
    for (int c = 0; c < NC1; ++c) {
      float v = row[c];
      v = (v >= T) ? v : 0.0f;
      if (v > tv[KCH - 1]) {
        float iv = v; int ic = c;
#pragma unroll
        for (int j = 0; j < KCH; ++j) {
          bool gt = iv > tv[j];
          float nv = gt ? iv : tv[j]; int nc = gt ? ic : tc[j];
          float ov = gt ? tv[j] : iv; int oc = gt ? tc[j] : ic;
          tv[j] = nv; tc[j] = nc; iv = ov; ic = oc;
        }
      }
    }
    float acc2[32];
#pragma unroll
    for (int e = 0; e < 32; ++e) acc2[e] = 0.f;
#pragma unroll
    for (int k = 0; k < KCH; ++k) {
      float v = tv[k];
      const float* cr = CEs + tc[k] * 33;
#pragma unroll
      for (int e = 0; e < 32; ++e) acc2[e] += v * cr[e];
    }
    float* op = seqo + ((size_t)b * HW + tid) * DD;
    const float* pr = pos + tid * DD;
#pragma unroll
    for (int e4 = 0; e4 < 8; ++e4) {
      float4 pv = ((const float4*)pr)[e4];
      float4 o;
      o.x = acc2[e4 * 4 + 0] * gi + pv.x;
      o.y = acc2[e4 * 4 + 1] * gi + pv.y;
      o.z = acc2[e4 * 4 + 2] * gi + pv.z;
      o.w = acc2[e4 * 4 + 3] * gi + pv.w;
      ((float4*)op)[e4] = o;
    }
  }
}

// ---------------- K4 (R10): MHA, block=sample, wave=head, lane=4 queries ----------
// K/V read ONCE per wave per t and reused across 4 queries (4x fewer LDS b128 than
// the per-head-block version); q rows computed and kept in the consuming lane's
// registers (no LDS round-trip); QKV weight-broadcast amortized over 2 rows.
__global__ __launch_bounds__(256, 4) void attn2_kernel(const float* __restrict__ seq,
                                                       const float* __restrict__ Wqkv,
                                                       const float* __restrict__ bqkv,
                                                       float* __restrict__ ctxo) {
  __shared__ alignas(16) float sK[NHD * HW * HDIM];   // [h][t][8], 25088 B
  __shared__ alignas(16) float sV[NHD * HW * HDIM];   // 25088 B
  __shared__ alignas(16) float sW[96 * 32];           // 12288 B
  __shared__ float sB[96];                            // total ~63 KB -> 2 blocks/CU
  int b = blockIdx.x, tid = threadIdx.x;
  int lane = tid & 63, h = tid >> 6;                  // wave = head

  for (int i = tid; i < 96 * 32 / 4; i += 256)
    ((float4*)sW)[i] = ((const float4*)Wqkv)[i];
  if (tid < 96) sB[tid] = bqkv[tid];
  __syncthreads();

  float q[4][8];
  float kk = 0.f;
  if (lane < 49) {
    for (int p = 0; p < 2; ++p) {                     // 2 passes x 2 rows
      int r0 = 4 * lane + 2 * p;
      float xr[2][32];
#pragma unroll
      for (int rr = 0; rr < 2; ++rr) {
        const float* sp = seq + ((size_t)b * HW + r0 + rr) * DD;
#pragma unroll
        for (int e = 0; e < 8; ++e) {
          float4 f = ((const float4*)sp)[e];
          xr[rr][e * 4 + 0] = f.x; xr[rr][e * 4 + 1] = f.y;
          xr[rr][e * 4 + 2] = f.z; xr[rr][e * 4 + 3] = f.w;
        }
      }
      // q outputs for head h (kept in registers)
#pragma unroll
      for (int d = 0; d < 8; ++d) {
        const float* wr = sW + (h * 8 + d) * 32;
        float bb = sB[h * 8 + d];
        float a0 = bb, a1 = bb;
#pragma unroll
        for (int e = 0; e < 32; e += 4) {
          float4 wv = *(const float4*)(wr + e);
          a0 += xr[0][e] * wv.x + xr[0][e + 1] * wv.y + xr[0][e + 2] * wv.z + xr[0][e + 3] * wv.w;
          a1 += xr[1][e] * wv.x + xr[1][e + 1] * wv.y + xr[1][e + 2] * wv.z + xr[1][e + 3] * wv.w;
        }
        q[2 * p + 0][d] = a0; q[2 * p + 1][d] = a1;
      }
      // k outputs -> LDS (+ |k|^2 tracking)
#pragma unroll
      for (int rr = 0; rr < 2; ++rr) {
        float k8[8]; float kkr = 0.f;
#pragma unroll
        for (int d = 0; d < 8; ++d) {
          const float* wr = sW + (32 + h * 8 + d) * 32;
          float a = sB[32 + h * 8 + d];
#pragma unroll
          for (int e = 0; e < 32; e += 4) {
            float4 wv = *(const float4*)(wr + e);
            a += xr[rr][e] * wv.x + xr[rr][e + 1] * wv.y + xr[rr][e + 2] * wv.z + xr[rr][e + 3] * wv.w;
          }
          k8[d] = a; kkr += a * a;
        }
        kk = fmaxf(kk, kkr);
        float* dst = sK + ((h * HW) + r0 + rr) * 8;
        float4 o0, o1;
        o0.x = k8[0]; o0.y = k8[1]; o0.z = k8[2]; o0.w = k8[3];
        o1.x = k8[4]; o1.y = k8[5]; o1.z = k8[6]; o1.w = k8[7];
        ((float4*)dst)[0] = o0; ((float4*)dst)[1] = o1;
      }
      // v outputs -> LDS (scalar writes keep register peak low)
#pragma unroll
      for (int rr = 0; rr < 2; ++rr) {
        float* dst = sV + ((h * HW) + r0 + rr) * 8;
#pragma unroll
        for (int d = 0; d < 8; ++d) {
          const float* wr = sW + (64 + h * 8 + d) * 32;
          float a = sB[64 + h * 8 + d];
#pragma unroll
          for (int e = 0; e < 32; e += 4) {
            float4 wv = *(const float4*)(wr + e);
            a += xr[rr][e] * wv.x + xr[rr][e + 1] * wv.y + xr[rr][e + 2] * wv.z + xr[rr][e + 3] * wv.w;
          }
          dst[d] = a;
        }
      }
    }
  }
#pragma unroll
  for (int off = 32; off >= 1; off >>= 1) kk = fmaxf(kk, __shfl_xor(kk, off));
  __syncthreads();
  if (lane >= 49) return;

  const float scale = 0.3535533905932738f;            // 1/sqrt(8)
  float km = sqrtf(kk) * scale;
  float negM[4], l[4], ctx[4][8];
#pragma unroll
  for (int i = 0; i < 4; ++i) {
    float qq = 0.f;
#pragma unroll
    for (int d = 0; d < 8; ++d) { qq += q[i][d] * q[i][d]; ctx[i][d] = 0.f; }
    negM[i] = -sqrtf(qq) * km;                        // <= -max score for query i
    l[i] = 0.f;
  }
  const float* kbase = sK + h * HW * 8;
  const float* vbase = sV + h * HW * 8;
#pragma unroll 2
  for (int t = 0; t < HW; ++t) {
    float4 ka = ((const float4*)(kbase + t * 8))[0];
    float4 kb2 = ((const float4*)(kbase + t * 8))[1];
    float4 va = ((const float4*)(vbase + t * 8))[0];
    float4 vb = ((const float4*)(vbase + t * 8))[1];
    float k8[8] = {ka.x, ka.y, ka.z, ka.w, kb2.x, kb2.y, kb2.z, kb2.w};
    float v8[8] = {va.x, va.y, va.z, va.w, vb.x, vb.y, vb.z, vb.w};
#pragma unroll
    for (int i = 0; i < 4; ++i) {
      float s = 0.f;
#pragma unroll
      for (int d = 0; d < 8; ++d) s += q[i][d] * k8[d];
      float pexp = __expf(fmaf(s, scale, negM[i]));   // arg <= 0
      l[i] += pexp;
#pragma unroll
      for (int d = 0; d < 8; ++d) ctx[i][d] += pexp * v8[d];
    }
  }
#pragma unroll
  for (int i = 0; i < 4; ++i) {
    float inv = 1.0f / l[i];
    float* op = ctxo + ((size_t)b * HW + 4 * lane + i) * DD + h * HDIM;
    float4 o0, o1;
    o0.x = ctx[i][0] * inv; o0.y = ctx[i][1] * inv; o0.z = ctx[i][2] * inv; o0.w = ctx[i][3] * inv;
    o1.x = ctx[i][4] * inv; o1.y = ctx[i][5] * inv; o1.z = ctx[i][6] * inv; o1.w = ctx[i][7] * inv;
    ((float4*)op)[0] = o0; ((float4*)op)[1] = o1;
  }
}

// ---------------- K5: out projection, 1 thread per row ----------------
__global__ __launch_bounds__(256) void outproj_kernel(const float* __restrict__ ctx,
                                                      const float* __restrict__ Wo,
                                                      const float* __restrict__ bo,
                                                      float* __restrict__ out) {
  __shared__ float sw[32 * 32];
  __shared__ float sb2[32];
  int tid = threadIdx.x;
  for (int i = tid; i < 1024; i += 256) sw[i] = Wo[i];
  if (tid < 32) sb2[tid] = bo[tid];
  __syncthreads();
  size_t row = (size_t)blockIdx.x * 256 + tid;
  const float* cr = ctx + row * 32;
  float xr[32];
#pragma unroll
  for (int e = 0; e < 8; ++e) {
    float4 f = ((const float4*)cr)[e];
    xr[e * 4 + 0] = f.x; xr[e * 4 + 1] = f.y; xr[e * 4 + 2] = f.z; xr[e * 4 + 3] = f.w;
  }
  float* op = out + row * 32;
#pragma unroll
  for (int d4 = 0; d4 < 8; ++d4) {
    float4 o;
    float* oo = (float*)&o;
#pragma unroll
    for (int q = 0; q < 4; ++q) {
      int d = d4 * 4 + q;
      float acc = sb2[d];
      const float* wr = sw + d * 32;
#pragma unroll
      for (int e = 0; e < 32; e += 4) {
        float4 wv = *(const float4*)(wr + e);
        acc += xr[e + 0] * wv.x + xr[e + 1] * wv.y + xr[e + 2] * wv.z + xr[e + 3] * wv.w;
      }
      oo[q] = acc;
    }
    ((float4*)op)[d4] = o;
  }
}

extern "C" void kernel_launch(void* const* d_in, const int* in_sizes, int n_in,
                              void* d_out, int out_size, void* d_ws, size_t ws_size,
                              hipStream_t stream) {
  const float* x  = (const float*)d_in[0];
  const float* cw = (const float*)d_in[1];
  const float* ce = (const float*)d_in[2];
  const float* wq = (const float*)d_in[3];
  const float* bq = (const float*)d_in[4];
  const float* wo = (const float*)d_in[5];
  const float* bo = (const float*)d_in[6];
  float* out = (float*)d_out;
  float* ws  = (float*)d_ws;

  // ws layout (floats): ctx [NB*HW*DD] | pos [196*32]
  float* ctx = ws;
  float* pos = ws + (size_t)NB * HW * DD;

  pos2d_kernel<<<(HW * DD + 255) / 256, 256, 0, stream>>>(pos);
  fused_kernel<<<NB, 1024, 0, stream>>>(x, cw, ce, pos, out);    // seq -> d_out
  attn2_kernel<<<NB, 256, 0, stream>>>(out, wq, bq, ctx);        // ctx -> ws
  outproj_kernel<<<(NB * HW * DD) / (256 * 32), 256, 0, stream>>>(ctx, wo, bo, out);
}